// Round 2
// baseline (720.483 us; speedup 1.0000x reference)
//
#include <hip/hip_runtime.h>
#include <hip/hip_bf16.h>

// Problem constants (from reference)
#define Hh    100
#define NN    1024     // B*L
#define BB    64
#define LL    16
#define EE    2048
#define NNODE 40000

typedef unsigned short u16;

__device__ __forceinline__ float bf2f(u16 u) {
    union { unsigned int i; float f; } v;
    v.i = ((unsigned int)u) << 16;
    return v.f;
}

__device__ __forceinline__ u16 f2bf(float f) {
    unsigned int x = __float_as_uint(f);
    unsigned int lsb = (x >> 16) & 1u;
    x += 0x7fffu + lsb;              // round-to-nearest-even
    return (u16)(x >> 16);
}

__device__ __forceinline__ float sigmoidf_(float x) {
    return 1.0f / (1.0f + expf(-x));
}

template <bool BF>
__device__ __forceinline__ float ldv(const void* p, size_t i) {
    if (BF) return bf2f(((const u16*)p)[i]);
    return ((const float*)p)[i];
}

// ---------------------------------------------------------------------------
// Detect input float dtype: bf16 data (|v| <= ~0.1) vs fp32 misread as bf16
// (low half-words are random bits -> many |v|>0.5 or NaN). flag=1 -> bf16.
__global__ void k_detect(const u16* __restrict__ embed, int* __restrict__ flag) {
    __shared__ int cnt;
    if (threadIdx.x == 0) cnt = 0;
    __syncthreads();
    int bad = 0;
    for (int i = threadIdx.x; i < 4096; i += 256) {
        float v = bf2f(embed[i]);
        if (!(fabsf(v) <= 0.5f)) bad++;   // counts NaN too
    }
    if (bad) atomicAdd(&cnt, bad);
    __syncthreads();
    if (threadIdx.x == 0) flag[0] = (cnt == 0) ? 1 : 0;
}

// ---------------------------------------------------------------------------
// Convert all small float tensors to fp32 into ws weight region.
template <bool BF>
__device__ void cvt_impl(int t,
                         const void* ew, const void* ggc, const void* wih, const void* whh,
                         const void* bih, const void* bhh, const void* W1w, const void* W1b,
                         const void* W2w, const void* W2b, const void* Wtw, const void* Wtb,
                         const void* qw, const void* qb, const void* W3w, const void* W3b,
                         float* __restrict__ W) {
    const void* src; int si; int doff;
    if      (t <   2048) { src = ew;  si = t;          doff = 0; }
    else if (t <  12048) { src = ggc; si = t - 2048;   doff = 2048; }
    else if (t <  42048) { src = wih; si = t - 12048;  doff = 12048; }
    else if (t <  72048) { src = whh; si = t - 42048;  doff = 42048; }
    else if (t <  72348) { src = bih; si = t - 72048;  doff = 72048; }
    else if (t <  72648) { src = bhh; si = t - 72348;  doff = 72352; }
    else if (t <  82648) { src = W1w; si = t - 72648;  doff = 72656; }
    else if (t <  82748) { src = W1b; si = t - 82648;  doff = 82656; }
    else if (t <  92748) { src = W2w; si = t - 82748;  doff = 82768; }
    else if (t <  92848) { src = W2b; si = t - 92748;  doff = 92768; }
    else if (t < 102848) { src = Wtw; si = t - 92848;  doff = 92880; }
    else if (t < 102948) { src = Wtb; si = t - 102848; doff = 102880; }
    else if (t < 103048) { src = qw;  si = t - 102948; doff = 102992; }
    else if (t < 103049) { src = qb;  si = t - 103048; doff = 103104; }
    else if (t < 123049) { src = W3w; si = t - 103049; doff = 103120; }
    else                 { src = W3b; si = t - 123049; doff = 123120; }
    W[doff + si] = ldv<BF>(src, si);
}

__global__ void k_cvt(const int* __restrict__ flag,
                      const void* ew, const void* ggc, const void* wih, const void* whh,
                      const void* bih, const void* bhh, const void* W1w, const void* W1b,
                      const void* W2w, const void* W2b, const void* Wtw, const void* Wtb,
                      const void* qw, const void* qb, const void* W3w, const void* W3b,
                      float* __restrict__ W) {
    int t = blockIdx.x * 256 + threadIdx.x;
    if (t >= 123149) return;
    if (flag[0]) cvt_impl<true >(t, ew, ggc, wih, whh, bih, bhh, W1w, W1b, W2w, W2b, Wtw, Wtb, qw, qb, W3w, W3b, W);
    else         cvt_impl<false>(t, ew, ggc, wih, whh, bih, bhh, W1w, W1b, W2w, W2b, Wtw, Wtb, qw, qb, W3w, W3b, W);
}

// ---------------------------------------------------------------------------
// h0 = embed[x] (fp32), agg = 0
__global__ void k_gather(const int* __restrict__ flag, const int* __restrict__ x,
                         const void* __restrict__ embed,
                         float* __restrict__ h0, float* __restrict__ agg) {
    int t = blockIdx.x * 256 + threadIdx.x;
    if (t < NN * Hh) {
        int i = t / Hh, j = t - i * Hh;
        size_t src = (size_t)x[i] * Hh + j;
        h0[t] = flag[0] ? ldv<true>(embed, src) : ldv<false>(embed, src);
        agg[t] = 0.0f;
    }
}

// m = h0 @ ggc_w[0]   (ggc_w row-major [k][j], fp32 in ws)
__global__ void k_m(const float* __restrict__ h0, const float* __restrict__ ggc_w,
                    float* __restrict__ m) {
    __shared__ float W[Hh * Hh];
    for (int idx = threadIdx.x; idx < Hh * Hh; idx += 256) W[idx] = ggc_w[idx];
    __syncthreads();
    int t = blockIdx.x * 256 + threadIdx.x;
    if (t >= NN * Hh) return;
    int i = t / Hh, j = t - i * Hh;
    const float* hr = h0 + i * Hh;
    float acc = 0.0f;
#pragma unroll 4
    for (int k = 0; k < Hh; ++k) acc += hr[k] * W[k * Hh + j];
    m[t] = acc;
}

// agg[dst[e]] += ew[e] * m[src[e]]
__global__ void k_scatter(const int* __restrict__ ei, const float* __restrict__ ew,
                          const float* __restrict__ m, float* __restrict__ agg) {
    int t = blockIdx.x * 256 + threadIdx.x;
    if (t >= EE * Hh) return;
    int e = t / Hh, j = t - e * Hh;
    int src = ei[e], dst = ei[EE + e];
    atomicAdd(&agg[dst * Hh + j], ew[e] * m[src * Hh + j]);
}

// GRU cell: h1 = GRU(agg as input, h0 as state)
__global__ void k_gru(const float* __restrict__ agg, const float* __restrict__ h0,
                      const float* __restrict__ wih, const float* __restrict__ whh,
                      const float* __restrict__ bih, const float* __restrict__ bhh,
                      float* __restrict__ h1) {
    int t = blockIdx.x * 256 + threadIdx.x;
    if (t >= NN * Hh) return;
    int i = t / Hh, j = t - i * Hh;
    const float4* ar  = reinterpret_cast<const float4*>(agg + i * Hh);
    const float4* hr  = reinterpret_cast<const float4*>(h0 + i * Hh);
    const float4* wir = reinterpret_cast<const float4*>(wih + (size_t)j * Hh);
    const float4* wiz = reinterpret_cast<const float4*>(wih + (size_t)(j + Hh) * Hh);
    const float4* win = reinterpret_cast<const float4*>(wih + (size_t)(j + 2 * Hh) * Hh);
    const float4* whr = reinterpret_cast<const float4*>(whh + (size_t)j * Hh);
    const float4* whz = reinterpret_cast<const float4*>(whh + (size_t)(j + Hh) * Hh);
    const float4* whn = reinterpret_cast<const float4*>(whh + (size_t)(j + 2 * Hh) * Hh);
    float s_ir = 0, s_iz = 0, s_in = 0, s_hr = 0, s_hz = 0, s_hn = 0;
    for (int kc = 0; kc < Hh / 4; ++kc) {
        float4 a = ar[kc];
        float4 h = hr[kc];
        float4 w;
        w = wir[kc]; s_ir += a.x * w.x + a.y * w.y + a.z * w.z + a.w * w.w;
        w = wiz[kc]; s_iz += a.x * w.x + a.y * w.y + a.z * w.z + a.w * w.w;
        w = win[kc]; s_in += a.x * w.x + a.y * w.y + a.z * w.z + a.w * w.w;
        w = whr[kc]; s_hr += h.x * w.x + h.y * w.y + h.z * w.z + h.w * w.w;
        w = whz[kc]; s_hz += h.x * w.x + h.y * w.y + h.z * w.z + h.w * w.w;
        w = whn[kc]; s_hn += h.x * w.x + h.y * w.y + h.z * w.z + h.w * w.w;
    }
    s_ir += bih[j];
    s_iz += bih[j + Hh];
    s_in += bih[j + 2 * Hh];
    s_hr += bhh[j];
    s_hz += bhh[j + Hh];
    s_hn += bhh[j + 2 * Hh];
    float r = sigmoidf_(s_ir + s_hr);
    float z = sigmoidf_(s_iz + s_hz);
    float n = tanhf(s_in + r * s_hn);
    h1[t] = (1.0f - z) * n + z * h0[t];
}

// q2 = v @ W2^T + b2 ; vt = v @ Wt^T + bt ; (rows<64) q1 = s_l @ W1^T + b1
__global__ void k_att1(const float* __restrict__ h1,
                       const float* __restrict__ W1w, const float* __restrict__ W1b,
                       const float* __restrict__ W2w, const float* __restrict__ W2b,
                       const float* __restrict__ Wtw, const float* __restrict__ Wtb,
                       float* __restrict__ q1, float* __restrict__ q2, float* __restrict__ vt) {
    int t = blockIdx.x * 256 + threadIdx.x;
    if (t >= NN * Hh) return;
    int i = t / Hh, j = t - i * Hh;
    const float4* vr = reinterpret_cast<const float4*>(h1 + i * Hh);
    const float4* w2 = reinterpret_cast<const float4*>(W2w + (size_t)j * Hh);
    const float4* wt = reinterpret_cast<const float4*>(Wtw + (size_t)j * Hh);
    float a2 = 0, at = 0;
    for (int kc = 0; kc < Hh / 4; ++kc) {
        float4 v = vr[kc];
        float4 w;
        w = w2[kc]; a2 += v.x * w.x + v.y * w.y + v.z * w.z + v.w * w.w;
        w = wt[kc]; at += v.x * w.x + v.y * w.y + v.z * w.z + v.w * w.w;
    }
    q2[t] = a2 + W2b[j];
    vt[t] = at + Wtb[j];
    if (i < BB) {
        const float4* sl = reinterpret_cast<const float4*>(h1 + (i * LL + LL - 1) * Hh);
        const float4* w1 = reinterpret_cast<const float4*>(W1w + (size_t)j * Hh);
        float a1 = 0;
        for (int kc = 0; kc < Hh / 4; ++kc) {
            float4 v = sl[kc];
            float4 w = w1[kc];
            a1 += v.x * w.x + v.y * w.y + v.z * w.z + v.w * w.w;
        }
        q1[i * Hh + j] = a1 + W1b[j];
    }
}

// alpha[i] = sum_j sigmoid(q1[b][j]+q2[i][j]) * qw[j] + qb
__global__ void k_alpha(const float* __restrict__ q1, const float* __restrict__ q2,
                        const float* __restrict__ qw, const float* __restrict__ qb,
                        float* __restrict__ alpha) {
    int i = blockIdx.x * 256 + threadIdx.x;
    if (i >= NN) return;
    int b = i >> 4;
    float acc = 0;
    for (int j = 0; j < Hh; ++j)
        acc += sigmoidf_(q1[b * Hh + j] + q2[i * Hh + j]) * qw[j];
    alpha[i] = acc + qb[0];
}

// per block b: s_g = sum_l alpha*v ; s_h = [s_l, s_g] @ W3^T + b3
__global__ void k_sgsh(const float* __restrict__ h1, const float* __restrict__ alpha,
                       const float* __restrict__ W3w, const float* __restrict__ W3b,
                       float* __restrict__ sh) {
    __shared__ float sl[Hh];
    __shared__ float sg[Hh];
    __shared__ float al[LL];
    int b = blockIdx.x;
    int j = threadIdx.x;   // blockDim = 128
    if (j < LL) al[j] = alpha[b * LL + j];
    __syncthreads();
    if (j < Hh) {
        sl[j] = h1[(b * LL + LL - 1) * Hh + j];
        float acc = 0;
#pragma unroll
        for (int l = 0; l < LL; ++l) acc += al[l] * h1[(b * LL + l) * Hh + j];
        sg[j] = acc;
    }
    __syncthreads();
    if (j < Hh) {
        float acc = W3b[j];
        const float* wr = W3w + (size_t)j * 2 * Hh;
        for (int k = 0; k < Hh; ++k) acc += sl[k] * wr[k];
        for (int k = 0; k < Hh; ++k) acc += sg[k] * wr[Hh + k];
        sh[b * Hh + j] = acc;
    }
}

// z[b][j] = s_h[b].e_j + sum_l softmax_l(e_j.vt[b][l]) * (e_j.v[b][l])
template <bool BF>
__device__ void final_impl(const void* __restrict__ embed,
                           const float* __restrict__ s_vt, const float* __restrict__ s_v,
                           const float* __restrict__ s_sh, void* __restrict__ out,
                           int b, int j) {
    float t[LL], c[LL];
    float sd = 0.0f;
#pragma unroll
    for (int l = 0; l < LL; ++l) { t[l] = 0.0f; c[l] = 0.0f; }
    for (int kc = 0; kc < Hh / 4; ++kc) {
        int k = kc * 4;
        float e0, e1, e2, e3;
        if (BF) {
            const u16* er = (const u16*)embed + (size_t)j * Hh;
            ushort4 u = *reinterpret_cast<const ushort4*>(er + k);  // 8B-aligned (row = 200B)
            e0 = bf2f(u.x); e1 = bf2f(u.y); e2 = bf2f(u.z); e3 = bf2f(u.w);
        } else {
            const float* er = (const float*)embed + (size_t)j * Hh;
            float4 u = *reinterpret_cast<const float4*>(er + k);    // 16B-aligned (row = 400B)
            e0 = u.x; e1 = u.y; e2 = u.z; e3 = u.w;
        }
#pragma unroll
        for (int l = 0; l < LL; ++l) {
            float4 a = *reinterpret_cast<const float4*>(s_vt + l * Hh + k);
            t[l] += e0 * a.x + e1 * a.y + e2 * a.z + e3 * a.w;
            float4 bb = *reinterpret_cast<const float4*>(s_v + l * Hh + k);
            c[l] += e0 * bb.x + e1 * bb.y + e2 * bb.z + e3 * bb.w;
        }
        float4 s4 = *reinterpret_cast<const float4*>(s_sh + k);
        sd += e0 * s4.x + e1 * s4.y + e2 * s4.z + e3 * s4.w;
    }
    float mx = t[0];
#pragma unroll
    for (int l = 1; l < LL; ++l) mx = fmaxf(mx, t[l]);
    float den = 0.0f, num = 0.0f;
#pragma unroll
    for (int l = 0; l < LL; ++l) {
        float p = expf(t[l] - mx);
        den += p;
        num += p * c[l];
    }
    float r = sd + num / den;
    if (BF) ((u16*)out)[(size_t)b * NNODE + j] = f2bf(r);
    else    ((float*)out)[(size_t)b * NNODE + j] = r;
}

__global__ void __launch_bounds__(256) k_final(const int* __restrict__ flag,
                                               const void* __restrict__ embed,
                                               const float* __restrict__ vt,
                                               const float* __restrict__ h1,
                                               const float* __restrict__ sh,
                                               void* __restrict__ out) {
    __shared__ alignas(16) float s_vt[LL * Hh];
    __shared__ alignas(16) float s_v[LL * Hh];
    __shared__ alignas(16) float s_sh[Hh];
    int b = blockIdx.y;
    for (int idx = threadIdx.x; idx < LL * Hh; idx += 256) {
        s_vt[idx] = vt[b * LL * Hh + idx];
        s_v[idx]  = h1[b * LL * Hh + idx];
    }
    for (int idx = threadIdx.x; idx < Hh; idx += 256) s_sh[idx] = sh[b * Hh + idx];
    __syncthreads();
    int j = blockIdx.x * 256 + threadIdx.x;
    if (j >= NNODE) return;
    if (flag[0]) final_impl<true >(embed, s_vt, s_v, s_sh, out, b, j);
    else         final_impl<false>(embed, s_vt, s_v, s_sh, out, b, j);
}

extern "C" void kernel_launch(void* const* d_in, const int* in_sizes, int n_in,
                              void* d_out, int out_size, void* d_ws, size_t ws_size,
                              hipStream_t stream) {
    const int* x      = (const int*)d_in[0];
    const int* ei     = (const int*)d_in[1];
    const void* ew    = d_in[2];
    // d_in[3] batch: unused by reference
    const void* embed = d_in[4];
    const void* ggc   = d_in[5];
    const void* wih   = d_in[6];
    const void* whh   = d_in[7];
    const void* bih   = d_in[8];
    const void* bhh   = d_in[9];
    const void* W1w   = d_in[10];
    const void* W1b   = d_in[11];
    const void* W2w   = d_in[12];
    const void* W2b   = d_in[13];
    const void* Wtw   = d_in[14];
    const void* Wtb   = d_in[15];
    const void* qw    = d_in[16];
    const void* qb    = d_in[17];
    const void* W3w   = d_in[18];
    const void* W3b   = d_in[19];
    float* ws = (float*)d_ws;
    int* flag = (int*)d_ws;          // ws[0]

    // ws layout (floats):
    //   [0..64)           flag + pad
    //   [64..64+123232)   fp32 weight region W
    //   [D..D+409600)     h0 | m | agg | h1   (D = 64+123232 = 123296)
    float* W = ws + 64;
    float* ew_f  = W + 0;
    float* ggc_f = W + 2048;
    float* wih_f = W + 12048;
    float* whh_f = W + 42048;
    float* bih_f = W + 72048;
    float* bhh_f = W + 72352;
    float* W1w_f = W + 72656;
    float* W1b_f = W + 82656;
    float* W2w_f = W + 82768;
    float* W2b_f = W + 92768;
    float* Wtw_f = W + 92880;
    float* Wtb_f = W + 102880;
    float* qw_f  = W + 102992;
    float* qb_f  = W + 103104;
    float* W3w_f = W + 103120;
    float* W3b_f = W + 123120;

    float* D     = ws + 123296;
    float* h0    = D;
    float* m     = D + 102400;
    float* agg   = D + 204800;
    float* h1    = D + 307200;
    // reuse after GRU:
    float* q1    = D;            // 6400
    float* alpha = D + 6400;     // 1024
    float* sh    = D + 8000;     // 6400
    float* q2    = m;
    float* vt    = agg;

    k_detect <<<dim3(1),   dim3(256), 0, stream>>>((const u16*)embed, flag);
    k_cvt    <<<dim3(482), dim3(256), 0, stream>>>(flag, ew, ggc, wih, whh, bih, bhh,
                                                   W1w, W1b, W2w, W2b, Wtw, Wtb, qw, qb, W3w, W3b, W);
    k_gather <<<dim3(400), dim3(256), 0, stream>>>(flag, x, embed, h0, agg);
    k_m      <<<dim3(400), dim3(256), 0, stream>>>(h0, ggc_f, m);
    k_scatter<<<dim3(800), dim3(256), 0, stream>>>(ei, ew_f, m, agg);
    k_gru    <<<dim3(400), dim3(256), 0, stream>>>(agg, h0, wih_f, whh_f, bih_f, bhh_f, h1);
    k_att1   <<<dim3(400), dim3(256), 0, stream>>>(h1, W1w_f, W1b_f, W2w_f, W2b_f, Wtw_f, Wtb_f, q1, q2, vt);
    k_alpha  <<<dim3(4),   dim3(256), 0, stream>>>(q1, q2, qw_f, qb_f, alpha);
    k_sgsh   <<<dim3(64),  dim3(128), 0, stream>>>(h1, alpha, W3w_f, W3b_f, sh);
    k_final  <<<dim3((NNODE + 255) / 256, BB), dim3(256), 0, stream>>>(flag, embed, vt, h1, sh, (void*)d_out);
}

// Round 5
// 442.038 us; speedup vs baseline: 1.6299x; 1.6299x over previous
//
#include <hip/hip_runtime.h>
#include <hip/hip_bf16.h>

// Problem constants (from reference)
#define Hh    100
#define NN    1024     // B*L
#define BB    64
#define LL    16
#define EE    2048
#define NNODE 40000

#define KP    128      // K padded to 4 MFMA steps of 32
#define PCOLS 48       // P rows (C-columns): 16 vt | 16 v | 1 sh | 15 zero
#define LROW  136      // LDS row stride in shorts (272 B)
#define DSTR  49       // D LDS row stride in floats

typedef unsigned short u16;
typedef __attribute__((ext_vector_type(8))) short short8;   // 8 bf16 = 4 VGPRs
typedef __attribute__((ext_vector_type(4))) float f32x4;    // MFMA C/D

__device__ __forceinline__ float bf2f(u16 u) {
    union { unsigned int i; float f; } v;
    v.i = ((unsigned int)u) << 16;
    return v.f;
}

__device__ __forceinline__ u16 f2bf(float f) {
    unsigned int x = __float_as_uint(f);
    unsigned int lsb = (x >> 16) & 1u;
    x += 0x7fffu + lsb;              // round-to-nearest-even
    return (u16)(x >> 16);
}

__device__ __forceinline__ float sigmoidf_(float x) {
    return 1.0f / (1.0f + expf(-x));
}

template <bool BF>
__device__ __forceinline__ float ldv(const void* p, size_t i) {
    if (BF) return bf2f(((const u16*)p)[i]);
    return ((const float*)p)[i];
}

// ---------------------------------------------------------------------------
// Detect input float dtype: bf16 data (|v| <= ~0.1) vs fp32 misread as bf16.
__global__ void k_detect(const u16* __restrict__ embed, int* __restrict__ flag) {
    __shared__ int cnt;
    if (threadIdx.x == 0) cnt = 0;
    __syncthreads();
    int bad = 0;
    for (int i = threadIdx.x; i < 4096; i += 256) {
        float v = bf2f(embed[i]);
        if (!(fabsf(v) <= 0.5f)) bad++;   // counts NaN too
    }
    if (bad) atomicAdd(&cnt, bad);
    __syncthreads();
    if (threadIdx.x == 0) flag[0] = (cnt == 0) ? 1 : 0;
}

// ---------------------------------------------------------------------------
// Convert all small float tensors to fp32 into ws weight region.
template <bool BF>
__device__ void cvt_impl(int t,
                         const void* ew, const void* ggc, const void* wih, const void* whh,
                         const void* bih, const void* bhh, const void* W1w, const void* W1b,
                         const void* W2w, const void* W2b, const void* Wtw, const void* Wtb,
                         const void* qw, const void* qb, const void* W3w, const void* W3b,
                         float* __restrict__ W) {
    const void* src; int si; int doff;
    if      (t <   2048) { src = ew;  si = t;          doff = 0; }
    else if (t <  12048) { src = ggc; si = t - 2048;   doff = 2048; }
    else if (t <  42048) { src = wih; si = t - 12048;  doff = 12048; }
    else if (t <  72048) { src = whh; si = t - 42048;  doff = 42048; }
    else if (t <  72348) { src = bih; si = t - 72048;  doff = 72048; }
    else if (t <  72648) { src = bhh; si = t - 72348;  doff = 72352; }
    else if (t <  82648) { src = W1w; si = t - 72648;  doff = 72656; }
    else if (t <  82748) { src = W1b; si = t - 82648;  doff = 82656; }
    else if (t <  92748) { src = W2w; si = t - 82748;  doff = 82768; }
    else if (t <  92848) { src = W2b; si = t - 92748;  doff = 92768; }
    else if (t < 102848) { src = Wtw; si = t - 92848;  doff = 92880; }
    else if (t < 102948) { src = Wtb; si = t - 102848; doff = 102880; }
    else if (t < 103048) { src = qw;  si = t - 102948; doff = 102992; }
    else if (t < 103049) { src = qb;  si = t - 103048; doff = 103104; }
    else if (t < 123049) { src = W3w; si = t - 103049; doff = 103120; }
    else                 { src = W3b; si = t - 123049; doff = 123120; }
    W[doff + si] = ldv<BF>(src, si);
}

__global__ void k_cvt(const int* __restrict__ flag,
                      const void* ew, const void* ggc, const void* wih, const void* whh,
                      const void* bih, const void* bhh, const void* W1w, const void* W1b,
                      const void* W2w, const void* W2b, const void* Wtw, const void* Wtb,
                      const void* qw, const void* qb, const void* W3w, const void* W3b,
                      float* __restrict__ W) {
    int t = blockIdx.x * 256 + threadIdx.x;
    if (t >= 123149) return;
    if (flag[0]) cvt_impl<true >(t, ew, ggc, wih, whh, bih, bhh, W1w, W1b, W2w, W2b, Wtw, Wtb, qw, qb, W3w, W3b, W);
    else         cvt_impl<false>(t, ew, ggc, wih, whh, bih, bhh, W1w, W1b, W2w, W2b, Wtw, Wtb, qw, qb, W3w, W3b, W);
}

// ---------------------------------------------------------------------------
// h0 = embed[x] (fp32), agg = 0
__global__ void k_gather(const int* __restrict__ flag, const int* __restrict__ x,
                         const void* __restrict__ embed,
                         float* __restrict__ h0, float* __restrict__ agg) {
    int t = blockIdx.x * 256 + threadIdx.x;
    if (t < NN * Hh) {
        int i = t / Hh, j = t - i * Hh;
        size_t src = (size_t)x[i] * Hh + j;
        h0[t] = flag[0] ? ldv<true>(embed, src) : ldv<false>(embed, src);
        agg[t] = 0.0f;
    }
}

// m = h0 @ ggc_w[0]
__global__ void k_m(const float* __restrict__ h0, const float* __restrict__ ggc_w,
                    float* __restrict__ m) {
    __shared__ float W[Hh * Hh];
    for (int idx = threadIdx.x; idx < Hh * Hh; idx += 256) W[idx] = ggc_w[idx];
    __syncthreads();
    int t = blockIdx.x * 256 + threadIdx.x;
    if (t >= NN * Hh) return;
    int i = t / Hh, j = t - i * Hh;
    const float* hr = h0 + i * Hh;
    float acc = 0.0f;
#pragma unroll 4
    for (int k = 0; k < Hh; ++k) acc += hr[k] * W[k * Hh + j];
    m[t] = acc;
}

// agg[dst[e]] += ew[e] * m[src[e]]
__global__ void k_scatter(const int* __restrict__ ei, const float* __restrict__ ew,
                          const float* __restrict__ m, float* __restrict__ agg) {
    int t = blockIdx.x * 256 + threadIdx.x;
    if (t >= EE * Hh) return;
    int e = t / Hh, j = t - e * Hh;
    int src = ei[e], dst = ei[EE + e];
    atomicAdd(&agg[dst * Hh + j], ew[e] * m[src * Hh + j]);
}

// GRU cell: h1 = GRU(agg as input, h0 as state)
__global__ void k_gru(const float* __restrict__ agg, const float* __restrict__ h0,
                      const float* __restrict__ wih, const float* __restrict__ whh,
                      const float* __restrict__ bih, const float* __restrict__ bhh,
                      float* __restrict__ h1) {
    int t = blockIdx.x * 256 + threadIdx.x;
    if (t >= NN * Hh) return;
    int i = t / Hh, j = t - i * Hh;
    const float4* ar  = reinterpret_cast<const float4*>(agg + i * Hh);
    const float4* hr  = reinterpret_cast<const float4*>(h0 + i * Hh);
    const float4* wir = reinterpret_cast<const float4*>(wih + (size_t)j * Hh);
    const float4* wiz = reinterpret_cast<const float4*>(wih + (size_t)(j + Hh) * Hh);
    const float4* win = reinterpret_cast<const float4*>(wih + (size_t)(j + 2 * Hh) * Hh);
    const float4* whr = reinterpret_cast<const float4*>(whh + (size_t)j * Hh);
    const float4* whz = reinterpret_cast<const float4*>(whh + (size_t)(j + Hh) * Hh);
    const float4* whn = reinterpret_cast<const float4*>(whh + (size_t)(j + 2 * Hh) * Hh);
    float s_ir = 0, s_iz = 0, s_in = 0, s_hr = 0, s_hz = 0, s_hn = 0;
    for (int kc = 0; kc < Hh / 4; ++kc) {
        float4 a = ar[kc];
        float4 h = hr[kc];
        float4 w;
        w = wir[kc]; s_ir += a.x * w.x + a.y * w.y + a.z * w.z + a.w * w.w;
        w = wiz[kc]; s_iz += a.x * w.x + a.y * w.y + a.z * w.z + a.w * w.w;
        w = win[kc]; s_in += a.x * w.x + a.y * w.y + a.z * w.z + a.w * w.w;
        w = whr[kc]; s_hr += h.x * w.x + h.y * w.y + h.z * w.z + h.w * w.w;
        w = whz[kc]; s_hz += h.x * w.x + h.y * w.y + h.z * w.z + h.w * w.w;
        w = whn[kc]; s_hn += h.x * w.x + h.y * w.y + h.z * w.z + h.w * w.w;
    }
    s_ir += bih[j];
    s_iz += bih[j + Hh];
    s_in += bih[j + 2 * Hh];
    s_hr += bhh[j];
    s_hz += bhh[j + Hh];
    s_hn += bhh[j + 2 * Hh];
    float r = sigmoidf_(s_ir + s_hr);
    float z = sigmoidf_(s_iz + s_hz);
    float n = tanhf(s_in + r * s_hn);
    h1[t] = (1.0f - z) * n + z * h0[t];
}

// q2 = v @ W2^T + b2 ; vt = v @ Wt^T + bt ; (rows<64) q1 = s_l @ W1^T + b1
__global__ void k_att1(const float* __restrict__ h1,
                       const float* __restrict__ W1w, const float* __restrict__ W1b,
                       const float* __restrict__ W2w, const float* __restrict__ W2b,
                       const float* __restrict__ Wtw, const float* __restrict__ Wtb,
                       float* __restrict__ q1, float* __restrict__ q2, float* __restrict__ vt) {
    int t = blockIdx.x * 256 + threadIdx.x;
    if (t >= NN * Hh) return;
    int i = t / Hh, j = t - i * Hh;
    const float4* vr = reinterpret_cast<const float4*>(h1 + i * Hh);
    const float4* w2 = reinterpret_cast<const float4*>(W2w + (size_t)j * Hh);
    const float4* wt = reinterpret_cast<const float4*>(Wtw + (size_t)j * Hh);
    float a2 = 0, at = 0;
    for (int kc = 0; kc < Hh / 4; ++kc) {
        float4 v = vr[kc];
        float4 w;
        w = w2[kc]; a2 += v.x * w.x + v.y * w.y + v.z * w.z + v.w * w.w;
        w = wt[kc]; at += v.x * w.x + v.y * w.y + v.z * w.z + v.w * w.w;
    }
    q2[t] = a2 + W2b[j];
    vt[t] = at + Wtb[j];
    if (i < BB) {
        const float4* sl = reinterpret_cast<const float4*>(h1 + (i * LL + LL - 1) * Hh);
        const float4* w1 = reinterpret_cast<const float4*>(W1w + (size_t)j * Hh);
        float a1 = 0;
        for (int kc = 0; kc < Hh / 4; ++kc) {
            float4 v = sl[kc];
            float4 w = w1[kc];
            a1 += v.x * w.x + v.y * w.y + v.z * w.z + v.w * w.w;
        }
        q1[i * Hh + j] = a1 + W1b[j];
    }
}

// alpha[i] = sum_j sigmoid(q1[b][j]+q2[i][j]) * qw[j] + qb
__global__ void k_alpha(const float* __restrict__ q1, const float* __restrict__ q2,
                        const float* __restrict__ qw, const float* __restrict__ qb,
                        float* __restrict__ alpha) {
    int i = blockIdx.x * 256 + threadIdx.x;
    if (i >= NN) return;
    int b = i >> 4;
    float acc = 0;
    for (int j = 0; j < Hh; ++j)
        acc += sigmoidf_(q1[b * Hh + j] + q2[i * Hh + j]) * qw[j];
    alpha[i] = acc + qb[0];
}

// per block b: s_g = sum_l alpha*v ; s_h = [s_l, s_g] @ W3^T + b3
__global__ void k_sgsh(const float* __restrict__ h1, const float* __restrict__ alpha,
                       const float* __restrict__ W3w, const float* __restrict__ W3b,
                       float* __restrict__ sh) {
    __shared__ float sl[Hh];
    __shared__ float sg[Hh];
    __shared__ float al[LL];
    int b = blockIdx.x;
    int j = threadIdx.x;   // blockDim = 128
    if (j < LL) al[j] = alpha[b * LL + j];
    __syncthreads();
    if (j < Hh) {
        sl[j] = h1[(b * LL + LL - 1) * Hh + j];
        float acc = 0;
#pragma unroll
        for (int l = 0; l < LL; ++l) acc += al[l] * h1[(b * LL + l) * Hh + j];
        sg[j] = acc;
    }
    __syncthreads();
    if (j < Hh) {
        float acc = W3b[j];
        const float* wr = W3w + (size_t)j * 2 * Hh;
        for (int k = 0; k < Hh; ++k) acc += sl[k] * wr[k];
        for (int k = 0; k < Hh; ++k) acc += sg[k] * wr[Hh + k];
        sh[b * Hh + j] = acc;
    }
}

// ---------------------------------------------------------------------------
// Build P[b][n][k] bf16: n 0..15 vt | 16..31 v | 32 sh | 33..47 zero; k>=100 zero
__global__ void k_prep(const float* __restrict__ vt, const float* __restrict__ h1,
                       const float* __restrict__ sh, u16* __restrict__ P) {
    int t = blockIdx.x * 256 + threadIdx.x;
    if (t >= BB * PCOLS * KP) return;
    int b = t / (PCOLS * KP);
    int r = t - b * (PCOLS * KP);
    int n = r / KP;
    int k = r - n * KP;
    float v = 0.0f;
    if (k < Hh) {
        if      (n < 16) v = vt[(b * LL + n) * Hh + k];
        else if (n < 32) v = h1[(b * LL + (n - 16)) * Hh + k];
        else if (n == 32) v = sh[b * Hh + k];
    }
    P[t] = f2bf(v);
}

// ---------------------------------------------------------------------------
// MFMA score kernel with runtime C/D-orientation probe + LDS round-trip
// epilogue (layout-agnostic, per m120's verified pattern).
__global__ void __launch_bounds__(256) k_score(const int* __restrict__ flag,
                                               const void* __restrict__ embed,
                                               const u16* __restrict__ P,
                                               void* __restrict__ out) {
    __shared__ alignas(16) u16 sE[128 * LROW];   // 34816 B; reused as D (128*49 f32)
    float* sD = (float*)sE;
    const int jb = blockIdx.x * 128;
    const int tid = threadIdx.x;
    const bool bf = (flag[0] != 0);

    // Stage embed tile -> LDS bf16
    if (bf) {
        const u16* eb = (const u16*)embed;
        for (int q = tid; q < 128 * 25; q += 256) {
            int r = q / 25, kc = q - r * 25;
            int j = jb + r;
            ushort4 u;
            if (j < NNODE) u = *((const ushort4*)(eb + (size_t)j * Hh) + kc);
            else { u.x = 0; u.y = 0; u.z = 0; u.w = 0; }
            *(ushort4*)&sE[r * LROW + kc * 4] = u;
        }
    } else {
        const float* eb = (const float*)embed;
        for (int q = tid; q < 128 * 25; q += 256) {
            int r = q / 25, kc = q - r * 25;
            int j = jb + r;
            ushort4 u;
            if (j < NNODE) {
                float4 f = *((const float4*)(eb + (size_t)j * Hh) + kc);
                u.x = f2bf(f.x); u.y = f2bf(f.y); u.z = f2bf(f.z); u.w = f2bf(f.w);
            } else { u.x = 0; u.y = 0; u.z = 0; u.w = 0; }
            *(ushort4*)&sE[r * LROW + kc * 4] = u;
        }
    }
    for (int q = tid; q < 128 * 7; q += 256) {
        int r = q / 7, c = q - r * 7;
        ushort4 z; z.x = 0; z.y = 0; z.z = 0; z.w = 0;
        *(ushort4*)&sE[r * LROW + Hh + c * 4] = z;
    }
    __syncthreads();

    const int wave = tid >> 6, lane = tid & 63;
    const int m = lane & 15, quad = lane >> 4;

    // A fragments (A[m=lane&15][k=quad*8+j], m120-verified); any k-permutation
    // error cancels since B uses the symmetric assumption.
    short8 A[2][4];
#pragma unroll
    for (int s = 0; s < 2; ++s)
#pragma unroll
        for (int k = 0; k < 4; ++k)
            A[s][k] = *(const short8*)&sE[(wave * 32 + s * 16 + m) * LROW + k * 32 + quad * 8];

    // --- Orientation probe: A[m][0]=m, B[0][n]=1 -> D[m][n]=m.
    // H1 (col=lane&15, row=quad*4+reg): lane0 regs = {0,1,2,3} -> pd[1]==1.0
    // H2 (transposed): lane0 regs = {m,m,m,m} = 0 -> pd[1]==0.0
    short8 pa = {0, 0, 0, 0, 0, 0, 0, 0};
    short8 pb = {0, 0, 0, 0, 0, 0, 0, 0};
    if (quad == 0) {
        pa[0] = (short)f2bf((float)m);
        pb[0] = (short)f2bf(1.0f);
    }
    f32x4 pd = (f32x4){0.0f, 0.0f, 0.0f, 0.0f};
    pd = __builtin_amdgcn_mfma_f32_16x16x32_bf16(pa, pb, pd, 0, 0, 0);
    const bool isH1 =
        (__builtin_amdgcn_readfirstlane(__float_as_uint(pd[1])) == 0x3f800000u);

    __syncthreads();   // all waves done reading sE before sD overwrites it

    for (int b = 0; b < BB; ++b) {
        const u16* Pb = P + (size_t)b * PCOLS * KP;
        short8 Bf[3][4];
#pragma unroll
        for (int t = 0; t < 3; ++t)
#pragma unroll
            for (int k = 0; k < 4; ++k)
                Bf[t][k] = *(const short8*)&Pb[(t * 16 + m) * KP + k * 32 + quad * 8];

        f32x4 acc[2][3];
#pragma unroll
        for (int s = 0; s < 2; ++s)
#pragma unroll
            for (int t = 0; t < 3; ++t)
                acc[s][t] = (f32x4){0.0f, 0.0f, 0.0f, 0.0f};

#pragma unroll
        for (int k = 0; k < 4; ++k)
#pragma unroll
            for (int s = 0; s < 2; ++s)
#pragma unroll
                for (int t = 0; t < 3; ++t)
                    acc[s][t] = __builtin_amdgcn_mfma_f32_16x16x32_bf16(A[s][k], Bf[t][k], acc[s][t], 0, 0, 0);

        // Write D to LDS at probed coordinates (wave-uniform branch)
        if (isH1) {
#pragma unroll
            for (int s = 0; s < 2; ++s)
#pragma unroll
                for (int t = 0; t < 3; ++t)
#pragma unroll
                    for (int r = 0; r < 4; ++r)
                        sD[(wave * 32 + s * 16 + quad * 4 + r) * DSTR + t * 16 + m] = acc[s][t][r];
        } else {
#pragma unroll
            for (int s = 0; s < 2; ++s)
#pragma unroll
                for (int t = 0; t < 3; ++t)
#pragma unroll
                    for (int r = 0; r < 4; ++r)
                        sD[(wave * 32 + s * 16 + m) * DSTR + t * 16 + quad * 4 + r] = acc[s][t][r];
        }
        __syncthreads();

        // Scalar epilogue: thread tid<128 owns embed row tid
        if (tid < 128) {
            int j = jb + tid;
            if (j < NNODE) {
                const float* Dr = &sD[tid * DSTR];
                float mx = Dr[0];
#pragma unroll
                for (int l = 1; l < 16; ++l) mx = fmaxf(mx, Dr[l]);
                float den = 0.0f, num = 0.0f;
#pragma unroll
                for (int l = 0; l < 16; ++l) {
                    float p = expf(Dr[l] - mx);
                    den += p;
                    num += p * Dr[16 + l];
                }
                float z = Dr[32] + num / den;
                if (bf) ((u16*)out)[(size_t)b * NNODE + j] = f2bf(z);
                else    ((float*)out)[(size_t)b * NNODE + j] = z;
            }
        }
        __syncthreads();
    }
}

extern "C" void kernel_launch(void* const* d_in, const int* in_sizes, int n_in,
                              void* d_out, int out_size, void* d_ws, size_t ws_size,
                              hipStream_t stream) {
    const int* x      = (const int*)d_in[0];
    const int* ei     = (const int*)d_in[1];
    const void* ew    = d_in[2];
    // d_in[3] batch: unused by reference
    const void* embed = d_in[4];
    const void* ggc   = d_in[5];
    const void* wih   = d_in[6];
    const void* whh   = d_in[7];
    const void* bih   = d_in[8];
    const void* bhh   = d_in[9];
    const void* W1w   = d_in[10];
    const void* W1b   = d_in[11];
    const void* W2w   = d_in[12];
    const void* W2b   = d_in[13];
    const void* Wtw   = d_in[14];
    const void* Wtb   = d_in[15];
    const void* qw    = d_in[16];
    const void* qb    = d_in[17];
    const void* W3w   = d_in[18];
    const void* W3b   = d_in[19];
    float* ws = (float*)d_ws;
    int* flag = (int*)d_ws;          // ws[0]

    // ws layout (floats):
    //   [0..64)           flag + pad
    //   [64..64+123232)   fp32 weight region W
    //   [D..D+409600)     h0 | m | agg | h1   (D = 123296)
    // Post-GRU reuse (R4 BUGFIX: sh is 64*100=6400 floats, NOT 1600; R3/R4
    // placed P at D+1600 which k_prep overwrote while reading sh -> race):
    //   sh    = D + 0      (6400)  written k_sgsh, read k_prep
    //   q1    = D + 6400   (6400)  dead after k_alpha
    //   alpha = D + 12800  (1024)  dead after k_sgsh
    //   P     = (u16*)(D + 6400), 393216 u16 = 196608 floats ->
    //           spans [D+6400, D+203008) : no overlap with sh [D,6400),
    //           vt (D+204800) or h1 (D+307200); overlays only dead q1/alpha/q2.
    float* W = ws + 64;
    float* ew_f  = W + 0;
    float* ggc_f = W + 2048;
    float* wih_f = W + 12048;
    float* whh_f = W + 42048;
    float* bih_f = W + 72048;
    float* bhh_f = W + 72352;
    float* W1w_f = W + 72656;
    float* W1b_f = W + 82656;
    float* W2w_f = W + 82768;
    float* W2b_f = W + 92768;
    float* Wtw_f = W + 92880;
    float* Wtb_f = W + 102880;
    float* qw_f  = W + 102992;
    float* qb_f  = W + 103104;
    float* W3w_f = W + 103120;
    float* W3b_f = W + 123120;

    float* D     = ws + 123296;
    float* h0    = D;
    float* m     = D + 102400;
    float* agg   = D + 204800;
    float* h1    = D + 307200;
    // reuse after GRU:
    float* sh    = D;            // 6400 floats (64 x 100)
    float* q1    = D + 6400;     // 6400
    float* alpha = D + 12800;    // 1024
    float* q2    = m;
    float* vt    = agg;
    u16*   P     = (u16*)(D + 6400);  // 393216 shorts, ends at D+203008 floats

    k_detect <<<dim3(1),    dim3(256), 0, stream>>>((const u16*)embed, flag);
    k_cvt    <<<dim3(482),  dim3(256), 0, stream>>>(flag, ew, ggc, wih, whh, bih, bhh,
                                                    W1w, W1b, W2w, W2b, Wtw, Wtb, qw, qb, W3w, W3b, W);
    k_gather <<<dim3(400),  dim3(256), 0, stream>>>(flag, x, embed, h0, agg);
    k_m      <<<dim3(400),  dim3(256), 0, stream>>>(h0, ggc_f, m);
    k_scatter<<<dim3(800),  dim3(256), 0, stream>>>(ei, ew_f, m, agg);
    k_gru    <<<dim3(400),  dim3(256), 0, stream>>>(agg, h0, wih_f, whh_f, bih_f, bhh_f, h1);
    k_att1   <<<dim3(400),  dim3(256), 0, stream>>>(h1, W1w_f, W1b_f, W2w_f, W2b_f, Wtw_f, Wtb_f, q1, q2, vt);
    k_alpha  <<<dim3(4),    dim3(256), 0, stream>>>(q1, q2, qw_f, qb_f, alpha);
    k_sgsh   <<<dim3(64),   dim3(128), 0, stream>>>(h1, alpha, W3w_f, W3b_f, sh);
    k_prep   <<<dim3(1536), dim3(256), 0, stream>>>(vt, h1, sh, P);
    k_score  <<<dim3((NNODE + 127) / 128), dim3(256), 0, stream>>>(flag, embed, P, d_out);
}

// Round 6
// 352.931 us; speedup vs baseline: 2.0414x; 1.2525x over previous
//
#include <hip/hip_runtime.h>
#include <hip/hip_bf16.h>

// Problem constants (from reference)
#define Hh    100
#define NN    1024     // B*L
#define BB    64
#define LL    16
#define EE    2048
#define NNODE 40000

#define KP    128      // K padded to 4 MFMA steps of 32
#define PCOLS 48       // P rows (C-columns): 16 vt | 16 v | 1 sh | 15 zero
#define LROW  136      // LDS row stride in shorts (272 B)
#define DSTR  34       // D LDS row stride in floats (4*34 % 32 == 8 -> 2-way only)
#define BSPL  4        // b-loop split across blockIdx.y
#define BPB   (BB / BSPL)

typedef unsigned short u16;
typedef __attribute__((ext_vector_type(8))) short short8;   // 8 bf16 = 4 VGPRs
typedef __attribute__((ext_vector_type(4))) float f32x4;    // MFMA C/D

__device__ __forceinline__ float bf2f(u16 u) {
    union { unsigned int i; float f; } v;
    v.i = ((unsigned int)u) << 16;
    return v.f;
}

__device__ __forceinline__ u16 f2bf(float f) {
    unsigned int x = __float_as_uint(f);
    unsigned int lsb = (x >> 16) & 1u;
    x += 0x7fffu + lsb;              // round-to-nearest-even
    return (u16)(x >> 16);
}

__device__ __forceinline__ float sigmoidf_(float x) {
    return 1.0f / (1.0f + expf(-x));
}

template <bool BF>
__device__ __forceinline__ float ldv(const void* p, size_t i) {
    if (BF) return bf2f(((const u16*)p)[i]);
    return ((const float*)p)[i];
}

// ---------------------------------------------------------------------------
// Detect input float dtype: bf16 data (|v| <= ~0.1) vs fp32 misread as bf16.
__global__ void k_detect(const u16* __restrict__ embed, int* __restrict__ flag) {
    __shared__ int cnt;
    if (threadIdx.x == 0) cnt = 0;
    __syncthreads();
    int bad = 0;
    for (int i = threadIdx.x; i < 4096; i += 256) {
        float v = bf2f(embed[i]);
        if (!(fabsf(v) <= 0.5f)) bad++;   // counts NaN too
    }
    if (bad) atomicAdd(&cnt, bad);
    __syncthreads();
    if (threadIdx.x == 0) flag[0] = (cnt == 0) ? 1 : 0;
}

// ---------------------------------------------------------------------------
// Convert all small float tensors to fp32 into ws weight region.
template <bool BF>
__device__ void cvt_impl(int t,
                         const void* ew, const void* ggc, const void* wih, const void* whh,
                         const void* bih, const void* bhh, const void* W1w, const void* W1b,
                         const void* W2w, const void* W2b, const void* Wtw, const void* Wtb,
                         const void* qw, const void* qb, const void* W3w, const void* W3b,
                         float* __restrict__ W) {
    const void* src; int si; int doff;
    if      (t <   2048) { src = ew;  si = t;          doff = 0; }
    else if (t <  12048) { src = ggc; si = t - 2048;   doff = 2048; }
    else if (t <  42048) { src = wih; si = t - 12048;  doff = 12048; }
    else if (t <  72048) { src = whh; si = t - 42048;  doff = 42048; }
    else if (t <  72348) { src = bih; si = t - 72048;  doff = 72048; }
    else if (t <  72648) { src = bhh; si = t - 72348;  doff = 72352; }
    else if (t <  82648) { src = W1w; si = t - 72648;  doff = 72656; }
    else if (t <  82748) { src = W1b; si = t - 82648;  doff = 82656; }
    else if (t <  92748) { src = W2w; si = t - 82748;  doff = 82768; }
    else if (t <  92848) { src = W2b; si = t - 92748;  doff = 92768; }
    else if (t < 102848) { src = Wtw; si = t - 92848;  doff = 92880; }
    else if (t < 102948) { src = Wtb; si = t - 102848; doff = 102880; }
    else if (t < 103048) { src = qw;  si = t - 102948; doff = 102992; }
    else if (t < 103049) { src = qb;  si = t - 103048; doff = 103104; }
    else if (t < 123049) { src = W3w; si = t - 103049; doff = 103120; }
    else                 { src = W3b; si = t - 123049; doff = 123120; }
    W[doff + si] = ldv<BF>(src, si);
}

__global__ void k_cvt(const int* __restrict__ flag,
                      const void* ew, const void* ggc, const void* wih, const void* whh,
                      const void* bih, const void* bhh, const void* W1w, const void* W1b,
                      const void* W2w, const void* W2b, const void* Wtw, const void* Wtb,
                      const void* qw, const void* qb, const void* W3w, const void* W3b,
                      float* __restrict__ W) {
    int t = blockIdx.x * 256 + threadIdx.x;
    if (t >= 123149) return;
    if (flag[0]) cvt_impl<true >(t, ew, ggc, wih, whh, bih, bhh, W1w, W1b, W2w, W2b, Wtw, Wtb, qw, qb, W3w, W3b, W);
    else         cvt_impl<false>(t, ew, ggc, wih, whh, bih, bhh, W1w, W1b, W2w, W2b, Wtw, Wtb, qw, qb, W3w, W3b, W);
}

// ---------------------------------------------------------------------------
// h0 = embed[x] (fp32), agg = 0
__global__ void k_gather(const int* __restrict__ flag, const int* __restrict__ x,
                         const void* __restrict__ embed,
                         float* __restrict__ h0, float* __restrict__ agg) {
    int t = blockIdx.x * 256 + threadIdx.x;
    if (t < NN * Hh) {
        int i = t / Hh, j = t - i * Hh;
        size_t src = (size_t)x[i] * Hh + j;
        h0[t] = flag[0] ? ldv<true>(embed, src) : ldv<false>(embed, src);
        agg[t] = 0.0f;
    }
}

// m = h0 @ ggc_w[0]
__global__ void k_m(const float* __restrict__ h0, const float* __restrict__ ggc_w,
                    float* __restrict__ m) {
    __shared__ float W[Hh * Hh];
    for (int idx = threadIdx.x; idx < Hh * Hh; idx += 256) W[idx] = ggc_w[idx];
    __syncthreads();
    int t = blockIdx.x * 256 + threadIdx.x;
    if (t >= NN * Hh) return;
    int i = t / Hh, j = t - i * Hh;
    const float* hr = h0 + i * Hh;
    float acc = 0.0f;
#pragma unroll 4
    for (int k = 0; k < Hh; ++k) acc += hr[k] * W[k * Hh + j];
    m[t] = acc;
}

// agg[dst[e]] += ew[e] * m[src[e]]
__global__ void k_scatter(const int* __restrict__ ei, const float* __restrict__ ew,
                          const float* __restrict__ m, float* __restrict__ agg) {
    int t = blockIdx.x * 256 + threadIdx.x;
    if (t >= EE * Hh) return;
    int e = t / Hh, j = t - e * Hh;
    int src = ei[e], dst = ei[EE + e];
    atomicAdd(&agg[dst * Hh + j], ew[e] * m[src * Hh + j]);
}

// GRU cell: h1 = GRU(agg as input, h0 as state)
__global__ void k_gru(const float* __restrict__ agg, const float* __restrict__ h0,
                      const float* __restrict__ wih, const float* __restrict__ whh,
                      const float* __restrict__ bih, const float* __restrict__ bhh,
                      float* __restrict__ h1) {
    int t = blockIdx.x * 256 + threadIdx.x;
    if (t >= NN * Hh) return;
    int i = t / Hh, j = t - i * Hh;
    const float4* ar  = reinterpret_cast<const float4*>(agg + i * Hh);
    const float4* hr  = reinterpret_cast<const float4*>(h0 + i * Hh);
    const float4* wir = reinterpret_cast<const float4*>(wih + (size_t)j * Hh);
    const float4* wiz = reinterpret_cast<const float4*>(wih + (size_t)(j + Hh) * Hh);
    const float4* win = reinterpret_cast<const float4*>(wih + (size_t)(j + 2 * Hh) * Hh);
    const float4* whr = reinterpret_cast<const float4*>(whh + (size_t)j * Hh);
    const float4* whz = reinterpret_cast<const float4*>(whh + (size_t)(j + Hh) * Hh);
    const float4* whn = reinterpret_cast<const float4*>(whh + (size_t)(j + 2 * Hh) * Hh);
    float s_ir = 0, s_iz = 0, s_in = 0, s_hr = 0, s_hz = 0, s_hn = 0;
    for (int kc = 0; kc < Hh / 4; ++kc) {
        float4 a = ar[kc];
        float4 h = hr[kc];
        float4 w;
        w = wir[kc]; s_ir += a.x * w.x + a.y * w.y + a.z * w.z + a.w * w.w;
        w = wiz[kc]; s_iz += a.x * w.x + a.y * w.y + a.z * w.z + a.w * w.w;
        w = win[kc]; s_in += a.x * w.x + a.y * w.y + a.z * w.z + a.w * w.w;
        w = whr[kc]; s_hr += h.x * w.x + h.y * w.y + h.z * w.z + h.w * w.w;
        w = whz[kc]; s_hz += h.x * w.x + h.y * w.y + h.z * w.z + h.w * w.w;
        w = whn[kc]; s_hn += h.x * w.x + h.y * w.y + h.z * w.z + h.w * w.w;
    }
    s_ir += bih[j];
    s_iz += bih[j + Hh];
    s_in += bih[j + 2 * Hh];
    s_hr += bhh[j];
    s_hz += bhh[j + Hh];
    s_hn += bhh[j + 2 * Hh];
    float r = sigmoidf_(s_ir + s_hr);
    float z = sigmoidf_(s_iz + s_hz);
    float n = tanhf(s_in + r * s_hn);
    h1[t] = (1.0f - z) * n + z * h0[t];
}

// ---------------------------------------------------------------------------
// Fused attention readout: per block b computes q1,q2,alpha,sg (LDS-local),
// writes vt (global, for k_prep) and sh (global). Replaces k_att1+k_alpha+k_sgsh.
__global__ void __launch_bounds__(256) k_att(const float* __restrict__ h1,
                    const float* __restrict__ W1w, const float* __restrict__ W1b,
                    const float* __restrict__ W2w, const float* __restrict__ W2b,
                    const float* __restrict__ Wtw, const float* __restrict__ Wtb,
                    const float* __restrict__ qw, const float* __restrict__ qb,
                    const float* __restrict__ W3w, const float* __restrict__ W3b,
                    float* __restrict__ vt, float* __restrict__ sh) {
    __shared__ float V[LL * Hh];
    __shared__ float Q2[LL * Hh];
    __shared__ float Q1[Hh];
    __shared__ float AL[LL];
    __shared__ float SG[Hh];
    const int b = blockIdx.x, tid = threadIdx.x;
    for (int idx = tid; idx < LL * Hh; idx += 256) V[idx] = h1[b * LL * Hh + idx];
    __syncthreads();
    for (int idx = tid; idx < LL * Hh; idx += 256) {
        int i = idx / Hh, j = idx - i * Hh;
        const float* vr = &V[i * Hh];
        const float* w2 = W2w + (size_t)j * Hh;
        const float* wt = Wtw + (size_t)j * Hh;
        float a2 = 0, at = 0;
        for (int k = 0; k < Hh; ++k) { a2 += vr[k] * w2[k]; at += vr[k] * wt[k]; }
        Q2[idx] = a2 + W2b[j];
        vt[b * LL * Hh + idx] = at + Wtb[j];
    }
    if (tid < Hh) {
        const float* sl = &V[(LL - 1) * Hh];
        const float* w1 = W1w + (size_t)tid * Hh;
        float a1 = 0;
        for (int k = 0; k < Hh; ++k) a1 += sl[k] * w1[k];
        Q1[tid] = a1 + W1b[tid];
    }
    __syncthreads();
    if (tid < LL) {
        float acc = 0;
        for (int j = 0; j < Hh; ++j)
            acc += sigmoidf_(Q1[j] + Q2[tid * Hh + j]) * qw[j];
        AL[tid] = acc + qb[0];
    }
    __syncthreads();
    if (tid < Hh) {
        float acc = 0;
#pragma unroll
        for (int l = 0; l < LL; ++l) acc += AL[l] * V[l * Hh + tid];
        SG[tid] = acc;
    }
    __syncthreads();
    if (tid < Hh) {
        float acc = W3b[tid];
        const float* wr = W3w + (size_t)tid * 2 * Hh;
        const float* sl = &V[(LL - 1) * Hh];
        for (int k = 0; k < Hh; ++k) acc += sl[k] * wr[k];
        for (int k = 0; k < Hh; ++k) acc += SG[k] * wr[Hh + k];
        sh[b * Hh + tid] = acc;
    }
}

// ---------------------------------------------------------------------------
// Build P[b][n][k] bf16: n 0..15 vt | 16..31 v | 32 sh | 33..47 zero; k>=100 zero
__global__ void k_prep(const float* __restrict__ vt, const float* __restrict__ h1,
                       const float* __restrict__ sh, u16* __restrict__ P) {
    int t = blockIdx.x * 256 + threadIdx.x;
    if (t >= BB * PCOLS * KP) return;
    int b = t / (PCOLS * KP);
    int r = t - b * (PCOLS * KP);
    int n = r / KP;
    int k = r - n * KP;
    float v = 0.0f;
    if (k < Hh) {
        if      (n < 16) v = vt[(b * LL + n) * Hh + k];
        else if (n < 32) v = h1[(b * LL + (n - 16)) * Hh + k];
        else if (n == 32) v = sh[b * Hh + k];
    }
    P[t] = f2bf(v);
}

// ---------------------------------------------------------------------------
// MFMA score kernel v2: barrier-free b-loop (wave-private D slices in a
// separate LDS region), 4-way b-split grid, all-lane __expf epilogue.
__global__ void __launch_bounds__(256) k_score(const int* __restrict__ flag,
                                               const void* __restrict__ embed,
                                               const u16* __restrict__ P,
                                               void* __restrict__ out) {
    __shared__ alignas(16) u16 sE[128 * LROW];          // 34816 B, stays intact
    __shared__ alignas(16) float sD[4][32 * DSTR];      // 17408 B, wave-private
    const int jb = blockIdx.x * 128;
    const int b0 = blockIdx.y * BPB;
    const int tid = threadIdx.x;
    const bool bf = (flag[0] != 0);

    // Stage embed tile -> LDS bf16
    if (bf) {
        const u16* eb = (const u16*)embed;
        for (int q = tid; q < 128 * 25; q += 256) {
            int r = q / 25, kc = q - r * 25;
            int j = jb + r;
            ushort4 u;
            if (j < NNODE) u = *((const ushort4*)(eb + (size_t)j * Hh) + kc);
            else { u.x = 0; u.y = 0; u.z = 0; u.w = 0; }
            *(ushort4*)&sE[r * LROW + kc * 4] = u;
        }
    } else {
        const float* eb = (const float*)embed;
        for (int q = tid; q < 128 * 25; q += 256) {
            int r = q / 25, kc = q - r * 25;
            int j = jb + r;
            ushort4 u;
            if (j < NNODE) {
                float4 f = *((const float4*)(eb + (size_t)j * Hh) + kc);
                u.x = f2bf(f.x); u.y = f2bf(f.y); u.z = f2bf(f.z); u.w = f2bf(f.w);
            } else { u.x = 0; u.y = 0; u.z = 0; u.w = 0; }
            *(ushort4*)&sE[r * LROW + kc * 4] = u;
        }
    }
    for (int q = tid; q < 128 * 7; q += 256) {
        int r = q / 7, c = q - r * 7;
        ushort4 z; z.x = 0; z.y = 0; z.z = 0; z.w = 0;
        *(ushort4*)&sE[r * LROW + Hh + c * 4] = z;
    }
    __syncthreads();   // only barrier in the kernel

    const int wave = tid >> 6, lane = tid & 63;
    const int m = lane & 15, quad = lane >> 4;
    float* Dw = sD[wave];

    // A fragments (A[m=lane&15][k=quad*8+j], m120-verified)
    short8 A[2][4];
#pragma unroll
    for (int s = 0; s < 2; ++s)
#pragma unroll
        for (int k = 0; k < 4; ++k)
            A[s][k] = *(const short8*)&sE[(wave * 32 + s * 16 + m) * LROW + k * 32 + quad * 8];

    // Orientation probe (cheap insurance): A[m][0]=m, B[0][n]=1 -> D[m][n]=m.
    short8 pa = {0, 0, 0, 0, 0, 0, 0, 0};
    short8 pb = {0, 0, 0, 0, 0, 0, 0, 0};
    if (quad == 0) {
        pa[0] = (short)f2bf((float)m);
        pb[0] = (short)f2bf(1.0f);
    }
    f32x4 pd = (f32x4){0.0f, 0.0f, 0.0f, 0.0f};
    pd = __builtin_amdgcn_mfma_f32_16x16x32_bf16(pa, pb, pd, 0, 0, 0);
    const bool isH1 =
        (__builtin_amdgcn_readfirstlane(__float_as_uint(pd[1])) == 0x3f800000u);

    const int rl = lane >> 1, half = lane & 1;   // epilogue row/half
    const float* Dr = &Dw[rl * DSTR];

    for (int bi = 0; bi < BPB; ++bi) {
        const int b = b0 + bi;
        const u16* Pb = P + (size_t)b * PCOLS * KP;
        short8 Bf[3][4];
#pragma unroll
        for (int t = 0; t < 3; ++t)
#pragma unroll
            for (int k = 0; k < 4; ++k)
                Bf[t][k] = *(const short8*)&Pb[(t * 16 + m) * KP + k * 32 + quad * 8];

        f32x4 acc[2][3];
#pragma unroll
        for (int s = 0; s < 2; ++s)
#pragma unroll
            for (int t = 0; t < 3; ++t)
                acc[s][t] = (f32x4){0.0f, 0.0f, 0.0f, 0.0f};

#pragma unroll
        for (int k = 0; k < 4; ++k)
#pragma unroll
            for (int s = 0; s < 2; ++s)
#pragma unroll
                for (int t = 0; t < 3; ++t)
                    acc[s][t] = __builtin_amdgcn_mfma_f32_16x16x32_bf16(A[s][k], Bf[t][k], acc[s][t], 0, 0, 0);

        // Wave-private D write (no barrier: same wave reads it back below)
        if (isH1) {
#pragma unroll
            for (int s = 0; s < 2; ++s)
#pragma unroll
                for (int t = 0; t < 3; ++t)
#pragma unroll
                    for (int r = 0; r < 4; ++r)
                        Dw[(s * 16 + quad * 4 + r) * DSTR + t * 16 + m] = acc[s][t][r];
        } else {
#pragma unroll
            for (int s = 0; s < 2; ++s)
#pragma unroll
                for (int t = 0; t < 3; ++t)
#pragma unroll
                    for (int r = 0; r < 4; ++r)
                        Dw[(s * 16 + m) * DSTR + t * 16 + quad * 4 + r] = acc[s][t][r];
        }

        // Epilogue: 2 lanes per row, 8 softmax cols each, combine via shfl_xor(1)
        float tv[8], cv[8];
#pragma unroll
        for (int c = 0; c < 8; ++c) {
            tv[c] = Dr[half * 8 + c];
            cv[c] = Dr[16 + half * 8 + c];
        }
        float mx = tv[0];
#pragma unroll
        for (int c = 1; c < 8; ++c) mx = fmaxf(mx, tv[c]);
        mx = fmaxf(mx, __shfl_xor(mx, 1));
        float den = 0.0f, num = 0.0f;
#pragma unroll
        for (int c = 0; c < 8; ++c) {
            float p = __expf(tv[c] - mx);
            den += p;
            num += p * cv[c];
        }
        den += __shfl_xor(den, 1);
        num += __shfl_xor(num, 1);
        if (half == 0) {
            int j = jb + wave * 32 + rl;
            if (j < NNODE) {
                float z = Dr[32] + num / den;
                if (bf) ((u16*)out)[(size_t)b * NNODE + j] = f2bf(z);
                else    ((float*)out)[(size_t)b * NNODE + j] = z;
            }
        }
    }
}

extern "C" void kernel_launch(void* const* d_in, const int* in_sizes, int n_in,
                              void* d_out, int out_size, void* d_ws, size_t ws_size,
                              hipStream_t stream) {
    const int* x      = (const int*)d_in[0];
    const int* ei     = (const int*)d_in[1];
    const void* ew    = d_in[2];
    // d_in[3] batch: unused by reference
    const void* embed = d_in[4];
    const void* ggc   = d_in[5];
    const void* wih   = d_in[6];
    const void* whh   = d_in[7];
    const void* bih   = d_in[8];
    const void* bhh   = d_in[9];
    const void* W1w   = d_in[10];
    const void* W1b   = d_in[11];
    const void* W2w   = d_in[12];
    const void* W2b   = d_in[13];
    const void* Wtw   = d_in[14];
    const void* Wtb   = d_in[15];
    const void* qw    = d_in[16];
    const void* qb    = d_in[17];
    const void* W3w   = d_in[18];
    const void* W3b   = d_in[19];
    float* ws = (float*)d_ws;
    int* flag = (int*)d_ws;          // ws[0]

    // ws layout (floats):
    //   [0..64)           flag + pad
    //   [64..64+123232)   fp32 weight region W
    //   [D..D+409600)     h0 | m | agg | h1   (D = 123296)
    // Post-GRU reuse: sh = D (6400 = 64x100, live through k_prep);
    // P = (u16*)(D+6400) spans [D+6400, D+203008) — overlays only dead
    // h0-remainder/m; vt (=agg, D+204800) and h1 (D+307200) untouched.
    float* W = ws + 64;
    float* ew_f  = W + 0;
    float* ggc_f = W + 2048;
    float* wih_f = W + 12048;
    float* whh_f = W + 42048;
    float* bih_f = W + 72048;
    float* bhh_f = W + 72352;
    float* W1w_f = W + 72656;
    float* W1b_f = W + 82656;
    float* W2w_f = W + 82768;
    float* W2b_f = W + 92768;
    float* Wtw_f = W + 92880;
    float* Wtb_f = W + 102880;
    float* qw_f  = W + 102992;
    float* qb_f  = W + 103104;
    float* W3w_f = W + 103120;
    float* W3b_f = W + 123120;

    float* D     = ws + 123296;
    float* h0    = D;
    float* m     = D + 102400;
    float* agg   = D + 204800;
    float* h1    = D + 307200;
    float* sh    = D;                 // 6400 floats (64 x 100)
    float* vt    = agg;
    u16*   P     = (u16*)(D + 6400);  // 393216 shorts, ends at D+203008 floats

    k_detect <<<dim3(1),    dim3(256), 0, stream>>>((const u16*)embed, flag);
    k_cvt    <<<dim3(482),  dim3(256), 0, stream>>>(flag, ew, ggc, wih, whh, bih, bhh,
                                                    W1w, W1b, W2w, W2b, Wtw, Wtb, qw, qb, W3w, W3b, W);
    k_gather <<<dim3(400),  dim3(256), 0, stream>>>(flag, x, embed, h0, agg);
    k_m      <<<dim3(400),  dim3(256), 0, stream>>>(h0, ggc_f, m);
    k_scatter<<<dim3(800),  dim3(256), 0, stream>>>(ei, ew_f, m, agg);
    k_gru    <<<dim3(400),  dim3(256), 0, stream>>>(agg, h0, wih_f, whh_f, bih_f, bhh_f, h1);
    k_att    <<<dim3(64),   dim3(256), 0, stream>>>(h1, W1w_f, W1b_f, W2w_f, W2b_f,
                                                    Wtw_f, Wtb_f, qw_f, qb_f, W3w_f, W3b_f, vt, sh);
    k_prep   <<<dim3(1536), dim3(256), 0, stream>>>(vt, h1, sh, P);
    k_score  <<<dim3((NNODE + 127) / 128, BSPL), dim3(256), 0, stream>>>(flag, embed, P, d_out);
}

// Round 7
// 266.780 us; speedup vs baseline: 2.7007x; 1.3229x over previous
//
#include <hip/hip_runtime.h>
#include <hip/hip_bf16.h>

// Problem constants (from reference)
#define Hh    100
#define NN    1024     // B*L
#define BB    64
#define LL    16
#define EE    2048
#define NNODE 40000

#define KP    128      // K padded to 4 MFMA steps of 32
#define PCOLS 48       // P rows (A-tiles): 16 vt | 16 v | 1 sh | 15 zero
#define PSTR  136      // LDS P row stride in shorts (272 B -> 2-way bank alias only)
#define BSPL  4        // b-loop split across blockIdx.y
#define BPB   (BB / BSPL)

typedef unsigned short u16;
typedef __attribute__((ext_vector_type(8))) short short8;   // 8 bf16 = 4 VGPRs
typedef __attribute__((ext_vector_type(4))) float f32x4;    // MFMA C/D

__device__ __forceinline__ float bf2f(u16 u) {
    union { unsigned int i; float f; } v;
    v.i = ((unsigned int)u) << 16;
    return v.f;
}

__device__ __forceinline__ u16 f2bf(float f) {
    unsigned int x = __float_as_uint(f);
    unsigned int lsb = (x >> 16) & 1u;
    x += 0x7fffu + lsb;              // round-to-nearest-even
    return (u16)(x >> 16);
}

__device__ __forceinline__ float sigmoidf_(float x) {
    return 1.0f / (1.0f + expf(-x));
}

template <bool BF>
__device__ __forceinline__ float ldv(const void* p, size_t i) {
    if (BF) return bf2f(((const u16*)p)[i]);
    return ((const float*)p)[i];
}

// ---------------------------------------------------------------------------
// k_cvt: per-block self-detect of input dtype + convert/transpose all small
// float tensors to fp32 in ws. Matrices used by k_gru/k_att are stored
// TRANSPOSED (dst[k*rows + r]) so their inner loops are lane-coalesced.
// Block 0 also publishes flag[0] (1 = bf16 inputs) for downstream kernels.
template <bool BF>
__device__ void cvt_impl(int t,
                         const void* ew, const void* ggc, const void* wih, const void* whh,
                         const void* bih, const void* bhh, const void* W1w, const void* W1b,
                         const void* W2w, const void* W2b, const void* Wtw, const void* Wtb,
                         const void* qw, const void* qb, const void* W3w, const void* W3b,
                         float* __restrict__ W) {
    const void* src; int si; int doff; int di;
    if      (t <   2048) { src = ew;  si = t;          doff = 0;      di = si; }
    else if (t <  12048) { src = ggc; si = t - 2048;   doff = 2048;   di = si; }                      // row-major (k_m)
    else if (t <  42048) { src = wih; si = t - 12048;  doff = 12048;  di = (si % 100) * 300 + si / 100; }   // T
    else if (t <  72048) { src = whh; si = t - 42048;  doff = 42048;  di = (si % 100) * 300 + si / 100; }   // T
    else if (t <  72348) { src = bih; si = t - 72048;  doff = 72048;  di = si; }
    else if (t <  72648) { src = bhh; si = t - 72348;  doff = 72352;  di = si; }
    else if (t <  82648) { src = W1w; si = t - 72648;  doff = 72656;  di = (si % 100) * 100 + si / 100; }   // T
    else if (t <  82748) { src = W1b; si = t - 82648;  doff = 82656;  di = si; }
    else if (t <  92748) { src = W2w; si = t - 82748;  doff = 82768;  di = (si % 100) * 100 + si / 100; }   // T
    else if (t <  92848) { src = W2b; si = t - 92748;  doff = 92768;  di = si; }
    else if (t < 102848) { src = Wtw; si = t - 92848;  doff = 92880;  di = (si % 100) * 100 + si / 100; }   // T
    else if (t < 102948) { src = Wtb; si = t - 102848; doff = 102880; di = si; }
    else if (t < 103048) { src = qw;  si = t - 102948; doff = 102992; di = si; }
    else if (t < 103049) { src = qb;  si = t - 103048; doff = 103104; di = si; }
    else if (t < 123049) { src = W3w; si = t - 103049; doff = 103120; di = (si % 200) * 100 + si / 200; }   // T
    else                 { src = W3b; si = t - 123049; doff = 123120; di = si; }
    W[doff + di] = ldv<BF>(src, si);
}

__global__ void __launch_bounds__(256) k_cvt(const void* embed_raw, int* __restrict__ flag,
                      const void* ew, const void* ggc, const void* wih, const void* whh,
                      const void* bih, const void* bhh, const void* W1w, const void* W1b,
                      const void* W2w, const void* W2b, const void* Wtw, const void* Wtb,
                      const void* qw, const void* qb, const void* W3w, const void* W3b,
                      float* __restrict__ W) {
    __shared__ int cnt;
    if (threadIdx.x == 0) cnt = 0;
    __syncthreads();
    int bad = 0;
    const u16* eb = (const u16*)embed_raw;
    for (int i = threadIdx.x; i < 4096; i += 256) {
        float v = bf2f(eb[i]);
        if (!(fabsf(v) <= 0.5f)) bad++;   // counts NaN too
    }
    if (bad) atomicAdd(&cnt, bad);
    __syncthreads();
    const bool bf = (cnt == 0);
    if (blockIdx.x == 0 && threadIdx.x == 0) flag[0] = bf ? 1 : 0;
    int t = blockIdx.x * 256 + threadIdx.x;
    if (t >= 123149) return;
    if (bf) cvt_impl<true >(t, ew, ggc, wih, whh, bih, bhh, W1w, W1b, W2w, W2b, Wtw, Wtb, qw, qb, W3w, W3b, W);
    else    cvt_impl<false>(t, ew, ggc, wih, whh, bih, bhh, W1w, W1b, W2w, W2b, Wtw, Wtb, qw, qb, W3w, W3b, W);
}

// ---------------------------------------------------------------------------
// h0 = embed[x] (fp32), agg = 0
__global__ void k_gather(const int* __restrict__ flag, const int* __restrict__ x,
                         const void* __restrict__ embed,
                         float* __restrict__ h0, float* __restrict__ agg) {
    int t = blockIdx.x * 256 + threadIdx.x;
    if (t < NN * Hh) {
        int i = t / Hh, j = t - i * Hh;
        size_t src = (size_t)x[i] * Hh + j;
        h0[t] = flag[0] ? ldv<true>(embed, src) : ldv<false>(embed, src);
        agg[t] = 0.0f;
    }
}

// m = h0 @ ggc_w[0]   (ggc row-major [k][j] in ws)
__global__ void k_m(const float* __restrict__ h0, const float* __restrict__ ggc_w,
                    float* __restrict__ m) {
    __shared__ float W[Hh * Hh];
    for (int idx = threadIdx.x; idx < Hh * Hh; idx += 256) W[idx] = ggc_w[idx];
    __syncthreads();
    int t = blockIdx.x * 256 + threadIdx.x;
    if (t >= NN * Hh) return;
    int i = t / Hh, j = t - i * Hh;
    const float* hr = h0 + i * Hh;
    float acc = 0.0f;
#pragma unroll 4
    for (int k = 0; k < Hh; ++k) acc += hr[k] * W[k * Hh + j];
    m[t] = acc;
}

// agg[dst[e]] += ew[e] * m[src[e]]
__global__ void k_scatter(const int* __restrict__ ei, const float* __restrict__ ew,
                          const float* __restrict__ m, float* __restrict__ agg) {
    int t = blockIdx.x * 256 + threadIdx.x;
    if (t >= EE * Hh) return;
    int e = t / Hh, j = t - e * Hh;
    int src = ei[e], dst = ei[EE + e];
    atomicAdd(&agg[dst * Hh + j], ew[e] * m[src * Hh + j]);
}

// GRU cell with TRANSPOSED weights (wihT/whhT: [k][r], r in 0..299) ->
// lane-coalesced weight reads (thread j reads wT[k*300 + j(+100,+200)]).
__global__ void k_gru(const float* __restrict__ agg, const float* __restrict__ h0,
                      const float* __restrict__ wihT, const float* __restrict__ whhT,
                      const float* __restrict__ bih, const float* __restrict__ bhh,
                      float* __restrict__ h1) {
    int t = blockIdx.x * 256 + threadIdx.x;
    if (t >= NN * Hh) return;
    int i = t / Hh, j = t - i * Hh;
    const float* ar = agg + i * Hh;
    const float* hr = h0 + i * Hh;
    float s_ir = 0, s_iz = 0, s_in = 0, s_hr = 0, s_hz = 0, s_hn = 0;
    for (int k = 0; k < Hh; ++k) {
        float a = ar[k], h = hr[k];
        const float* wT = wihT + k * 300;
        const float* uT = whhT + k * 300;
        s_ir += a * wT[j];
        s_iz += a * wT[j + 100];
        s_in += a * wT[j + 200];
        s_hr += h * uT[j];
        s_hz += h * uT[j + 100];
        s_hn += h * uT[j + 200];
    }
    s_ir += bih[j];
    s_iz += bih[j + Hh];
    s_in += bih[j + 2 * Hh];
    s_hr += bhh[j];
    s_hz += bhh[j + Hh];
    s_hn += bhh[j + 2 * Hh];
    float r = sigmoidf_(s_ir + s_hr);
    float z = sigmoidf_(s_iz + s_hz);
    float n = tanhf(s_in + r * s_hn);
    h1[t] = (1.0f - z) * n + z * h0[t];
}

// ---------------------------------------------------------------------------
// Fused attention readout + P build. Per block b: q1,q2,alpha,sg,sh,vt all
// LDS-local (transposed weights -> coalesced); writes P[b] (48x128 bf16)
// directly: n 0..15 vt | 16..31 v | 32 sh | 33..47 zero; k>=100 zero.
__global__ void __launch_bounds__(256) k_att(const float* __restrict__ h1,
                    const float* __restrict__ W1T, const float* __restrict__ W1b,
                    const float* __restrict__ W2T, const float* __restrict__ W2b,
                    const float* __restrict__ WtT, const float* __restrict__ Wtb,
                    const float* __restrict__ qw, const float* __restrict__ qb,
                    const float* __restrict__ W3T, const float* __restrict__ W3b,
                    u16* __restrict__ P) {
    __shared__ float V[LL * Hh];
    __shared__ float Q2[LL * Hh];
    __shared__ float VT[LL * Hh];
    __shared__ float Q1[Hh];
    __shared__ float AL[LL];
    __shared__ float SG[Hh];
    __shared__ float SH[Hh];
    const int b = blockIdx.x, tid = threadIdx.x;
    for (int idx = tid; idx < LL * Hh; idx += 256) V[idx] = h1[b * LL * Hh + idx];
    __syncthreads();
    for (int idx = tid; idx < LL * Hh; idx += 256) {
        int i = idx / Hh, j = idx - i * Hh;
        float a2 = 0, at = 0;
        for (int k = 0; k < Hh; ++k) {
            float vk = V[i * Hh + k];
            a2 += vk * W2T[k * Hh + j];
            at += vk * WtT[k * Hh + j];
        }
        Q2[idx] = a2 + W2b[j];
        VT[idx] = at + Wtb[j];
    }
    if (tid < Hh) {
        float a1 = 0;
        for (int k = 0; k < Hh; ++k) a1 += V[(LL - 1) * Hh + k] * W1T[k * Hh + tid];
        Q1[tid] = a1 + W1b[tid];
    }
    __syncthreads();
    if (tid < LL) {
        float acc = 0;
        for (int j = 0; j < Hh; ++j)
            acc += sigmoidf_(Q1[j] + Q2[tid * Hh + j]) * qw[j];
        AL[tid] = acc + qb[0];
    }
    __syncthreads();
    if (tid < Hh) {
        float acc = 0;
#pragma unroll
        for (int l = 0; l < LL; ++l) acc += AL[l] * V[l * Hh + tid];
        SG[tid] = acc;
    }
    __syncthreads();
    if (tid < Hh) {
        float acc = W3b[tid];
        for (int k = 0; k < Hh; ++k) acc += V[(LL - 1) * Hh + k] * W3T[k * Hh + tid];
        for (int k = 0; k < Hh; ++k) acc += SG[k] * W3T[(Hh + k) * Hh + tid];
        SH[tid] = acc;
    }
    __syncthreads();
    for (int e = tid; e < PCOLS * KP; e += 256) {
        int n = e >> 7, k = e & 127;
        float v = 0.0f;
        if (k < Hh) {
            if      (n < 16) v = VT[n * Hh + k];
            else if (n < 32) v = V[(n - 16) * Hh + k];
            else if (n == 32) v = SH[k];
        }
        P[(size_t)b * PCOLS * KP + e] = f2bf(v);
    }
}

// ---------------------------------------------------------------------------
// k_score v3: embed rows are the MFMA **B** operand (register-resident, loaded
// once per block), P tiles are the **A** operand staged per-b into a
// double-buffered padded LDS panel shared by all 4 waves. Softmax epilogue is
// pure shfl_xor(16/32) cross-quad reduction — no LDS round-trip, 1 barrier/iter.
__device__ __forceinline__ short8 load_efrag(const void* embed, bool bf, int j, int k0) {
    short8 v = {0, 0, 0, 0, 0, 0, 0, 0};
    if (j >= NNODE || k0 >= Hh) return v;
    if (bf) {
        const u16* row = (const u16*)embed + (size_t)j * Hh + k0;
        if (k0 + 8 <= Hh) {
            ushort4 a = *(const ushort4*)(row);       // 8B-aligned always
            ushort4 b = *(const ushort4*)(row + 4);
            v[0] = (short)a.x; v[1] = (short)a.y; v[2] = (short)a.z; v[3] = (short)a.w;
            v[4] = (short)b.x; v[5] = (short)b.y; v[6] = (short)b.z; v[7] = (short)b.w;
        } else {
            for (int e = 0; e < Hh - k0; ++e) v[e] = (short)row[e];
        }
    } else {
        const float* row = (const float*)embed + (size_t)j * Hh + k0;
        if (k0 + 8 <= Hh) {
            float4 a = *(const float4*)(row);          // 16B-aligned (400j + 4k0, k0 mult of 8)
            float4 b = *(const float4*)(row + 4);
            v[0] = (short)f2bf(a.x); v[1] = (short)f2bf(a.y); v[2] = (short)f2bf(a.z); v[3] = (short)f2bf(a.w);
            v[4] = (short)f2bf(b.x); v[5] = (short)f2bf(b.y); v[6] = (short)f2bf(b.z); v[7] = (short)f2bf(b.w);
        } else {
            for (int e = 0; e < Hh - k0; ++e) v[e] = (short)f2bf(row[e]);
        }
    }
    return v;
}

__device__ __forceinline__ void stage_P(const u16* __restrict__ P, int b,
                                        u16* __restrict__ dst, int tid) {
    const uint4* s4 = (const uint4*)(P + (size_t)b * (PCOLS * KP));   // 768 uint4
#pragma unroll
    for (int it = 0; it < 3; ++it) {
        int f = tid + it * 256;
        int row = f >> 4, off = f & 15;
        *(uint4*)&dst[row * PSTR + off * 8] = s4[f];
    }
}

__global__ void __launch_bounds__(256) k_score(const int* __restrict__ flag,
                                               const void* __restrict__ embed,
                                               const u16* __restrict__ P,
                                               void* __restrict__ out) {
    __shared__ alignas(16) u16 sP[2][PCOLS * PSTR];   // 2 x 13056 B
    const int jb = blockIdx.x * 128;
    const int b0 = blockIdx.y * BPB;
    const int tid = threadIdx.x;
    const bool bf = (flag[0] != 0);
    const int wave = tid >> 6, lane = tid & 63;
    const int m = lane & 15, quad = lane >> 4;

    // B fragments: 2 groups of 16 embed rows per wave, registers, loaded once.
    short8 Bf[2][4];
#pragma unroll
    for (int g = 0; g < 2; ++g)
#pragma unroll
        for (int ks = 0; ks < 4; ++ks)
            Bf[g][ks] = load_efrag(embed, bf, jb + wave * 32 + g * 16 + m, ks * 32 + quad * 8);

    // C/D orientation probe: A[m][0]=m, B[0][n]=1 -> D[m][n]=m.
    short8 pa = {0, 0, 0, 0, 0, 0, 0, 0};
    short8 pb = {0, 0, 0, 0, 0, 0, 0, 0};
    if (quad == 0) {
        pa[0] = (short)f2bf((float)m);
        pb[0] = (short)f2bf(1.0f);
    }
    f32x4 pd = (f32x4){0.0f, 0.0f, 0.0f, 0.0f};
    pd = __builtin_amdgcn_mfma_f32_16x16x32_bf16(pa, pb, pd, 0, 0, 0);
    const bool isH1 =
        (__builtin_amdgcn_readfirstlane(__float_as_uint(pd[1])) == 0x3f800000u);

    stage_P(P, b0, sP[0], tid);
    int cur = 0;
    for (int bi = 0; bi < BPB; ++bi) {
        const int b = b0 + bi;
        __syncthreads();                               // sP[cur] ready for all waves
        if (bi + 1 < BPB) stage_P(P, b + 1, sP[cur ^ 1], tid);

        const u16* sPc = sP[cur];
        short8 Af[3][4];
#pragma unroll
        for (int t = 0; t < 3; ++t)
#pragma unroll
            for (int ks = 0; ks < 4; ++ks)
                Af[t][ks] = *(const short8*)&sPc[(t * 16 + m) * PSTR + ks * 32 + quad * 8];

        f32x4 acc[2][3];
#pragma unroll
        for (int g = 0; g < 2; ++g)
#pragma unroll
            for (int t = 0; t < 3; ++t)
                acc[g][t] = (f32x4){0.0f, 0.0f, 0.0f, 0.0f};

#pragma unroll
        for (int ks = 0; ks < 4; ++ks)
#pragma unroll
            for (int g = 0; g < 2; ++g)
#pragma unroll
                for (int t = 0; t < 3; ++t)
                    acc[g][t] = __builtin_amdgcn_mfma_f32_16x16x32_bf16(Af[t][ks], Bf[g][ks], acc[g][t], 0, 0, 0);

        // Epilogue. D[m'][n]: m' = P row (tile-local), n = embed row (group-local).
#pragma unroll
        for (int g = 0; g < 2; ++g) {
            if (isH1) {
                // col = lane&15 = n ; row = quad*4+reg = m'
                float mx = fmaxf(fmaxf(acc[g][0][0], acc[g][0][1]), fmaxf(acc[g][0][2], acc[g][0][3]));
                mx = fmaxf(mx, __shfl_xor(mx, 16));
                mx = fmaxf(mx, __shfl_xor(mx, 32));
                float den = 0.0f, num = 0.0f;
#pragma unroll
                for (int r = 0; r < 4; ++r) {
                    float p = __expf(acc[g][0][r] - mx);
                    den += p;
                    num += p * acc[g][1][r];
                }
                den += __shfl_xor(den, 16); num += __shfl_xor(num, 16);
                den += __shfl_xor(den, 32); num += __shfl_xor(num, 32);
                if (quad == 0) {
                    int j = jb + wave * 32 + g * 16 + m;
                    if (j < NNODE) {
                        float z = acc[g][2][0] + num / den;    // sd = tile2 row 0 (quad0,reg0)
                        if (bf) ((u16*)out)[(size_t)b * NNODE + j] = f2bf(z);
                        else    ((float*)out)[(size_t)b * NNODE + j] = z;
                    }
                }
            } else {
                // transposed: row = lane&15 = m' ; col = quad*4+reg = n
                float mx[4], den[4], num[4];
#pragma unroll
                for (int r = 0; r < 4; ++r) mx[r] = acc[g][0][r];
#pragma unroll
                for (int s = 1; s <= 8; s <<= 1)
#pragma unroll
                    for (int r = 0; r < 4; ++r) mx[r] = fmaxf(mx[r], __shfl_xor(mx[r], s));
#pragma unroll
                for (int r = 0; r < 4; ++r) {
                    float p = __expf(acc[g][0][r] - mx[r]);
                    den[r] = p;
                    num[r] = p * acc[g][1][r];
                }
#pragma unroll
                for (int s = 1; s <= 8; s <<= 1)
#pragma unroll
                    for (int r = 0; r < 4; ++r) {
                        den[r] += __shfl_xor(den[r], s);
                        num[r] += __shfl_xor(num[r], s);
                    }
                if (m == 0) {
#pragma unroll
                    for (int r = 0; r < 4; ++r) {
                        int j = jb + wave * 32 + g * 16 + quad * 4 + r;
                        if (j < NNODE) {
                            float z = acc[g][2][r] + num[r] / den[r];
                            if (bf) ((u16*)out)[(size_t)b * NNODE + j] = f2bf(z);
                            else    ((float*)out)[(size_t)b * NNODE + j] = z;
                        }
                    }
                }
            }
        }
        cur ^= 1;
    }
}

extern "C" void kernel_launch(void* const* d_in, const int* in_sizes, int n_in,
                              void* d_out, int out_size, void* d_ws, size_t ws_size,
                              hipStream_t stream) {
    const int* x      = (const int*)d_in[0];
    const int* ei     = (const int*)d_in[1];
    const void* ew    = d_in[2];
    // d_in[3] batch: unused by reference
    const void* embed = d_in[4];
    const void* ggc   = d_in[5];
    const void* wih   = d_in[6];
    const void* whh   = d_in[7];
    const void* bih   = d_in[8];
    const void* bhh   = d_in[9];
    const void* W1w   = d_in[10];
    const void* W1b   = d_in[11];
    const void* W2w   = d_in[12];
    const void* W2b   = d_in[13];
    const void* Wtw   = d_in[14];
    const void* Wtb   = d_in[15];
    const void* qw    = d_in[16];
    const void* qb    = d_in[17];
    const void* W3w   = d_in[18];
    const void* W3b   = d_in[19];
    float* ws = (float*)d_ws;
    int* flag = (int*)d_ws;          // ws[0]

    // ws layout (floats):
    //   [0..64)           flag + pad
    //   [64..64+123232)   fp32 weight region W (gru/att matrices TRANSPOSED)
    //   [D..D+409600)     h0 | m | agg | h1   (D = 123296)
    // P (bf16, 393216 shorts = 196608 floats) overlays m+agg slots
    // [D+102400, D+299008): m dead after k_scatter, agg dead after k_gru;
    // k_att (writer) reads only h1 (D+307200) — no overlap.
    float* W = ws + 64;
    float* ew_f  = W + 0;
    float* ggc_f = W + 2048;
    float* wihT  = W + 12048;
    float* whhT  = W + 42048;
    float* bih_f = W + 72048;
    float* bhh_f = W + 72352;
    float* W1T   = W + 72656;
    float* W1b_f = W + 82656;
    float* W2T   = W + 82768;
    float* W2b_f = W + 92768;
    float* WtT   = W + 92880;
    float* Wtb_f = W + 102880;
    float* qw_f  = W + 102992;
    float* qb_f  = W + 103104;
    float* W3T   = W + 103120;
    float* W3b_f = W + 123120;

    float* D     = ws + 123296;
    float* h0    = D;
    float* m     = D + 102400;
    float* agg   = D + 204800;
    float* h1    = D + 307200;
    u16*   P     = (u16*)(D + 102400);

    k_cvt    <<<dim3(482),  dim3(256), 0, stream>>>(embed, flag, ew, ggc, wih, whh, bih, bhh,
                                                    W1w, W1b, W2w, W2b, Wtw, Wtb, qw, qb, W3w, W3b, W);
    k_gather <<<dim3(400),  dim3(256), 0, stream>>>(flag, x, embed, h0, agg);
    k_m      <<<dim3(400),  dim3(256), 0, stream>>>(h0, ggc_f, m);
    k_scatter<<<dim3(800),  dim3(256), 0, stream>>>(ei, ew_f, m, agg);
    k_gru    <<<dim3(400),  dim3(256), 0, stream>>>(agg, h0, wihT, whhT, bih_f, bhh_f, h1);
    k_att    <<<dim3(64),   dim3(256), 0, stream>>>(h1, W1T, W1b_f, W2T, W2b_f, WtT, Wtb_f,
                                                    qw_f, qb_f, W3T, W3b_f, P);
    k_score  <<<dim3((NNODE + 127) / 128, BSPL), dim3(256), 0, stream>>>(flag, embed, P, d_out);
}